// Round 1
// baseline (2740.387 us; speedup 1.0000x reference)
//
#include <hip/hip_runtime.h>
#include <hip/hip_bf16.h>

#define FM 64

// ---------------- CSR build ----------------

__global__ __launch_bounds__(256) void k_zero2(int* a, int na, int* b, int nb) {
    int i0 = blockIdx.x * blockDim.x + threadIdx.x;
    int stride = gridDim.x * blockDim.x;
    for (int i = i0; i < na; i += stride) a[i] = 0;
    for (int i = i0; i < nb; i += stride) b[i] = 0;
}

__global__ __launch_bounds__(256) void k_hist(const int* __restrict__ row, const int* __restrict__ col,
                                              int nnz, int* cnt_row, int* cnt_col) {
    int i0 = blockIdx.x * blockDim.x + threadIdx.x;
    int stride = gridDim.x * blockDim.x;
    for (int i = i0; i < nnz; i += stride) {
        atomicAdd(&cnt_col[col[i]], 1);
        atomicAdd(&cnt_row[row[i]], 1);
    }
}

// One block per scan problem (blockIdx.x == 0 -> A, == 1 -> B). 1024 threads.
__global__ __launch_bounds__(1024) void k_scan2(const int* cntA, int nA, int* ptrA, int* nxtA,
                                                const int* cntB, int nB, int* ptrB, int* nxtB) {
    const int* cnt = (blockIdx.x == 0) ? cntA : cntB;
    int n          = (blockIdx.x == 0) ? nA   : nB;
    int* ptr       = (blockIdx.x == 0) ? ptrA : ptrB;
    int* nxt       = (blockIdx.x == 0) ? nxtA : nxtB;

    __shared__ int wsum[17];
    __shared__ int carry, tot;
    if (threadIdx.x == 0) carry = 0;
    __syncthreads();

    int lane = threadIdx.x & 63;
    int wid  = threadIdx.x >> 6;

    for (int base = 0; base < n; base += 1024) {
        int idx = base + (int)threadIdx.x;
        int v = (idx < n) ? cnt[idx] : 0;
        int inc = v;
        #pragma unroll
        for (int off = 1; off < 64; off <<= 1) {
            int t = __shfl_up(inc, (unsigned)off, 64);
            if (lane >= off) inc += t;
        }
        if (lane == 63) wsum[wid] = inc;
        __syncthreads();
        if (threadIdx.x == 0) {
            int s = 0;
            for (int w = 0; w < 16; w++) { int t = wsum[w]; wsum[w] = s; s += t; }
            tot = s;
        }
        __syncthreads();
        int excl = carry + wsum[wid] + (inc - v);
        if (idx < n) { ptr[idx] = excl; nxt[idx] = excl; }
        __syncthreads();
        if (threadIdx.x == 0) carry += tot;
        __syncthreads();
    }
    if (threadIdx.x == 0) ptr[n] = carry;
}

__global__ __launch_bounds__(256) void k_place(const int* __restrict__ row, const int* __restrict__ col,
                                               const float* __restrict__ adj, int nnz,
                                               int* nxt_col, int* cs_src, float* cs_val,
                                               int* nxt_row, int* rv_src, float* rv_val) {
    int i0 = blockIdx.x * blockDim.x + threadIdx.x;
    int stride = gridDim.x * blockDim.x;
    for (int i = i0; i < nnz; i += stride) {
        int r = row[i], c = col[i];
        float v = fabsf(adj[i]);
        int p = atomicAdd(&nxt_col[c], 1);
        cs_src[p] = r; cs_val[p] = v;
        int q = atomicAdd(&nxt_row[r], 1);
        rv_src[q] = c; rv_val[q] = v;
    }
}

// ---------------- feature init ----------------

__global__ __launch_bounds__(256) void k_ones(float4* p, int n4) {
    int i0 = blockIdx.x * blockDim.x + threadIdx.x;
    int stride = gridDim.x * blockDim.x;
    float4 one = make_float4(1.f, 1.f, 1.f, 1.f);
    for (int i = i0; i < n4; i += stride) p[i] = one;
}

// prepare_cond MLP: 1 -> 128 (relu) -> 64.  block = 128 threads.
__global__ __launch_bounds__(128) void k_pc(const float* __restrict__ cond, float* __restrict__ constraints,
                                            int C,
                                            const float* __restrict__ w1, const float* __restrict__ b1,
                                            const float* __restrict__ w2, const float* __restrict__ b2) {
    __shared__ float hs[128];
    __shared__ float ps[128];
    int j = threadIdx.x;
    int jj = j & 63, part = j >> 6;
    float w1j = w1[j];
    float b1j = b1[j];
    float w2col[64];
    #pragma unroll
    for (int k = 0; k < 64; k++) w2col[k] = w2[(part * 64 + k) * 64 + jj];
    float b2j = (part == 0) ? b2[jj] : 0.f;

    for (int r = blockIdx.x; r < C; r += gridDim.x) {
        float c = cond[r];
        hs[j] = fmaxf(fmaf(c, w1j, b1j), 0.f);
        __syncthreads();
        float o0 = b2j, o1 = 0.f, o2 = 0.f, o3 = 0.f;
        #pragma unroll
        for (int k = 0; k < 64; k += 4) {
            int kk = part * 64 + k;
            o0 = fmaf(hs[kk],     w2col[k],     o0);
            o1 = fmaf(hs[kk + 1], w2col[k + 1], o1);
            o2 = fmaf(hs[kk + 2], w2col[k + 2], o2);
            o3 = fmaf(hs[kk + 3], w2col[k + 3], o3);
        }
        ps[j] = (o0 + o1) + (o2 + o3);
        __syncthreads();
        if (j < 64) constraints[r * 64 + j] = ps[j] + ps[64 + j];
        __syncthreads();
    }
}

// ---------------- segment-sum (gather form) ----------------
// One wave per destination row; lane = feature.
__global__ __launch_bounds__(256) void k_gather(const int* __restrict__ ptr,
                                                const int* __restrict__ src_idx,
                                                const float* __restrict__ vals,
                                                const float* __restrict__ src_feat,
                                                float* __restrict__ dst_feat, int n) {
    int wid = (int)((blockIdx.x * blockDim.x + threadIdx.x) >> 6);
    int lane = threadIdx.x & 63;
    int nw = (int)((gridDim.x * blockDim.x) >> 6);
    for (int d = wid; d < n; d += nw) {
        int s = ptr[d], e = ptr[d + 1];
        float a0 = 0.f, a1 = 0.f;
        int i = s;
        for (; i + 1 < e; i += 2) {
            int s0 = src_idx[i], s1 = src_idx[i + 1];
            float v0 = vals[i], v1 = vals[i + 1];
            a0 = fmaf(v0, src_feat[s0 * 64 + lane], a0);
            a1 = fmaf(v1, src_feat[s1 * 64 + lane], a1);
        }
        if (i < e) a0 = fmaf(vals[i], src_feat[src_idx[i] * 64 + lane], a0);
        dst_feat[d * 64 + lane] = a0 + a1;
    }
}

// ---------------- update MLP: concat(feat, msg) [128] -> 128 (relu) -> 64, in-place into feat
// block = 128 threads. W1 column per thread in regs (128), W2 half-column per thread (64).
__global__ __launch_bounds__(128) void k_mlp_update(float* __restrict__ feat, const float* __restrict__ msg,
                                                    int n,
                                                    const float* __restrict__ w1, const float* __restrict__ b1,
                                                    const float* __restrict__ w2, const float* __restrict__ b2) {
    __shared__ float xs[128];
    __shared__ float hs[128];
    __shared__ float ps[128];
    int j = threadIdx.x;
    int jj = j & 63, part = j >> 6;

    float wcol[128];
    #pragma unroll
    for (int k = 0; k < 128; k++) wcol[k] = w1[k * 128 + j];
    float w2col[64];
    #pragma unroll
    for (int k = 0; k < 64; k++) w2col[k] = w2[(part * 64 + k) * 64 + jj];
    float b1j = b1[j];
    float b2j = (part == 0) ? b2[jj] : 0.f;

    for (int r = blockIdx.x; r < n; r += gridDim.x) {
        float xv = (j < 64) ? feat[r * 64 + j] : msg[r * 64 + jj];
        __syncthreads();          // previous iteration done with xs
        xs[j] = xv;
        __syncthreads();
        float h0 = b1j, h1 = 0.f, h2 = 0.f, h3 = 0.f;
        #pragma unroll
        for (int k = 0; k < 128; k += 4) {
            h0 = fmaf(xs[k],     wcol[k],     h0);
            h1 = fmaf(xs[k + 1], wcol[k + 1], h1);
            h2 = fmaf(xs[k + 2], wcol[k + 2], h2);
            h3 = fmaf(xs[k + 3], wcol[k + 3], h3);
        }
        hs[j] = fmaxf((h0 + h1) + (h2 + h3), 0.f);
        __syncthreads();
        float o0 = b2j, o1 = 0.f, o2 = 0.f, o3 = 0.f;
        #pragma unroll
        for (int k = 0; k < 64; k += 4) {
            int kk = part * 64 + k;
            o0 = fmaf(hs[kk],     w2col[k],     o0);
            o1 = fmaf(hs[kk + 1], w2col[k + 1], o1);
            o2 = fmaf(hs[kk + 2], w2col[k + 2], o2);
            o3 = fmaf(hs[kk + 3], w2col[k + 3], o3);
        }
        ps[j] = (o0 + o1) + (o2 + o3);
        __syncthreads();
        if (j < 64) feat[r * 64 + j] = ps[j] + ps[64 + j];
    }
}

// ---------------- output MLP: 64 -> 128 (relu) -> 16, sigmoid ----------------
__global__ __launch_bounds__(128) void k_out(const float* __restrict__ vars, float* __restrict__ out, int V,
                                             const float* __restrict__ w1, const float* __restrict__ b1,
                                             const float* __restrict__ w2, const float* __restrict__ b2) {
    __shared__ float xs[64];
    __shared__ float hs[128];
    __shared__ float ps[128];
    int j = threadIdx.x;
    int jj16 = j & 15, part = j >> 4;   // 8 parts x 16 outputs

    float wcol[64];
    #pragma unroll
    for (int k = 0; k < 64; k++) wcol[k] = w1[k * 128 + j];
    float b1j = b1[j];
    float w2col[16];
    #pragma unroll
    for (int k = 0; k < 16; k++) w2col[k] = w2[(part * 16 + k) * 16 + jj16];
    float b2j = (j < 16) ? b2[j] : 0.f;

    for (int r = blockIdx.x; r < V; r += gridDim.x) {
        if (j < 64) xs[j] = vars[r * 64 + j];
        __syncthreads();
        float h0 = b1j, h1 = 0.f, h2 = 0.f, h3 = 0.f;
        #pragma unroll
        for (int k = 0; k < 64; k += 4) {
            h0 = fmaf(xs[k],     wcol[k],     h0);
            h1 = fmaf(xs[k + 1], wcol[k + 1], h1);
            h2 = fmaf(xs[k + 2], wcol[k + 2], h2);
            h3 = fmaf(xs[k + 3], wcol[k + 3], h3);
        }
        hs[j] = fmaxf((h0 + h1) + (h2 + h3), 0.f);
        __syncthreads();
        float o = 0.f;
        #pragma unroll
        for (int k = 0; k < 16; k++) o = fmaf(hs[part * 16 + k], w2col[k], o);
        ps[j] = o;
        __syncthreads();
        if (j < 16) {
            float s = b2j;
            #pragma unroll
            for (int p = 0; p < 8; p++) s += ps[p * 16 + j];
            out[r * 16 + j] = 1.f / (1.f + expf(-s));
        }
        __syncthreads();
    }
}

// ---------------- launch ----------------

extern "C" void kernel_launch(void* const* d_in, const int* in_sizes, int n_in,
                              void* d_out, int out_size, void* d_ws, size_t ws_size,
                              hipStream_t stream) {
    const int*   row_idx = (const int*)d_in[0];
    const int*   col_idx = (const int*)d_in[1];
    const float* adj     = (const float*)d_in[2];
    const float* cond    = (const float*)d_in[3];
    const float* pc_w1  = (const float*)d_in[6];
    const float* pc_b1  = (const float*)d_in[7];
    const float* pc_w2  = (const float*)d_in[8];
    const float* pc_b2  = (const float*)d_in[9];
    const float* cu_w1  = (const float*)d_in[10];
    const float* cu_b1  = (const float*)d_in[11];
    const float* cu_w2  = (const float*)d_in[12];
    const float* cu_b2  = (const float*)d_in[13];
    const float* vu_w1  = (const float*)d_in[14];
    const float* vu_b1  = (const float*)d_in[15];
    const float* vu_w2  = (const float*)d_in[16];
    const float* vu_b2  = (const float*)d_in[17];
    const float* out_w1 = (const float*)d_in[18];
    const float* out_b1 = (const float*)d_in[19];
    const float* out_w2 = (const float*)d_in[20];
    const float* out_b2 = (const float*)d_in[21];

    const int NNZ = in_sizes[0];
    const int C   = in_sizes[3];
    const int V   = out_size / 16;

    float* out = (float*)d_out;

    // ---- workspace carve ----
    char* wsb = (char*)d_ws;
    size_t off = 0;
    auto carve = [&](size_t bytes) -> void* {
        void* p = wsb + off;
        off = (off + bytes + 255) & ~(size_t)255;
        return p;
    };
    float* variables   = (float*)carve((size_t)V * 64 * 4);
    float* constraints = (float*)carve((size_t)C * 64 * 4);
    float* v2c         = (float*)carve((size_t)C * 64 * 4);
    float* c2v         = (float*)carve((size_t)V * 64 * 4);
    int*   cnt_col     = (int*)carve((size_t)C * 4);
    int*   cnt_row     = (int*)carve((size_t)V * 4);
    int*   col_ptr     = (int*)carve((size_t)(C + 1) * 4);
    int*   row_ptr     = (int*)carve((size_t)(V + 1) * 4);
    int*   col_nxt     = (int*)carve((size_t)C * 4);
    int*   row_nxt     = (int*)carve((size_t)V * 4);
    int*   cs_src      = (int*)carve((size_t)NNZ * 4);
    float* cs_val      = (float*)carve((size_t)NNZ * 4);
    int*   rv_src      = (int*)carve((size_t)NNZ * 4);
    float* rv_val      = (float*)carve((size_t)NNZ * 4);
    (void)ws_size; (void)n_in;

    // ---- CSR build (both orientations) ----
    k_zero2<<<256, 256, 0, stream>>>(cnt_col, C, cnt_row, V);
    k_hist<<<2048, 256, 0, stream>>>(row_idx, col_idx, NNZ, cnt_row, cnt_col);
    k_scan2<<<2, 1024, 0, stream>>>(cnt_col, C, col_ptr, col_nxt,
                                    cnt_row, V, row_ptr, row_nxt);
    k_place<<<2048, 256, 0, stream>>>(row_idx, col_idx, adj, NNZ,
                                      col_nxt, cs_src, cs_val,
                                      row_nxt, rv_src, rv_val);

    // ---- init features ----
    k_ones<<<2048, 256, 0, stream>>>((float4*)variables, V * 16);
    k_pc<<<2048, 128, 0, stream>>>(cond, constraints, C, pc_w1, pc_b1, pc_w2, pc_b2);

    // ---- message-passing rounds ----
    for (int p = 0; p < 3; p++) {
        k_gather<<<2048, 256, 0, stream>>>(col_ptr, cs_src, cs_val, variables, v2c, C);
        k_mlp_update<<<2048, 128, 0, stream>>>(constraints, v2c, C, cu_w1, cu_b1, cu_w2, cu_b2);
        k_gather<<<2048, 256, 0, stream>>>(row_ptr, rv_src, rv_val, constraints, c2v, V);
        k_mlp_update<<<2048, 128, 0, stream>>>(variables, c2v, V, vu_w1, vu_b1, vu_w2, vu_b2);
    }

    // ---- output ----
    k_out<<<2048, 128, 0, stream>>>(variables, out, V, out_w1, out_b1, out_w2, out_b2);
}

// Round 2
// 1794.463 us; speedup vs baseline: 1.5271x; 1.5271x over previous
//
#include <hip/hip_runtime.h>
#include <hip/hip_bf16.h>

#define FM 64

__device__ __forceinline__ float4 ld4(const float* p) { return *reinterpret_cast<const float4*>(p); }
__device__ __forceinline__ void st4(float* p, float4 v) { *reinterpret_cast<float4*>(p) = v; }
__device__ __forceinline__ void fma4(float4& a, float s, const float4 w) {
    a.x = fmaf(s, w.x, a.x); a.y = fmaf(s, w.y, a.y);
    a.z = fmaf(s, w.z, a.z); a.w = fmaf(s, w.w, a.w);
}

// ---------------- CSR build ----------------

__global__ __launch_bounds__(256) void k_zero2(int* a, int na, int* b, int nb) {
    int i0 = blockIdx.x * blockDim.x + threadIdx.x;
    int stride = gridDim.x * blockDim.x;
    for (int i = i0; i < na; i += stride) a[i] = 0;
    for (int i = i0; i < nb; i += stride) b[i] = 0;
}

__global__ __launch_bounds__(256) void k_hist(const int* __restrict__ row, const int* __restrict__ col,
                                              int nnz, int* cnt_row, int* cnt_col) {
    int i0 = blockIdx.x * blockDim.x + threadIdx.x;
    int stride = gridDim.x * blockDim.x;
    for (int i = i0; i < nnz; i += stride) {
        atomicAdd(&cnt_col[col[i]], 1);
        atomicAdd(&cnt_row[row[i]], 1);
    }
}

// One block per scan problem (blockIdx.x == 0 -> A, == 1 -> B). 1024 threads.
__global__ __launch_bounds__(1024) void k_scan2(const int* cntA, int nA, int* ptrA, int* nxtA,
                                                const int* cntB, int nB, int* ptrB, int* nxtB) {
    const int* cnt = (blockIdx.x == 0) ? cntA : cntB;
    int n          = (blockIdx.x == 0) ? nA   : nB;
    int* ptr       = (blockIdx.x == 0) ? ptrA : ptrB;
    int* nxt       = (blockIdx.x == 0) ? nxtA : nxtB;

    __shared__ int wsum[17];
    __shared__ int carry, tot;
    if (threadIdx.x == 0) carry = 0;
    __syncthreads();

    int lane = threadIdx.x & 63;
    int wid  = threadIdx.x >> 6;

    for (int base = 0; base < n; base += 1024) {
        int idx = base + (int)threadIdx.x;
        int v = (idx < n) ? cnt[idx] : 0;
        int inc = v;
        #pragma unroll
        for (int off = 1; off < 64; off <<= 1) {
            int t = __shfl_up(inc, (unsigned)off, 64);
            if (lane >= off) inc += t;
        }
        if (lane == 63) wsum[wid] = inc;
        __syncthreads();
        if (threadIdx.x == 0) {
            int s = 0;
            for (int w = 0; w < 16; w++) { int t = wsum[w]; wsum[w] = s; s += t; }
            tot = s;
        }
        __syncthreads();
        int excl = carry + wsum[wid] + (inc - v);
        if (idx < n) { ptr[idx] = excl; nxt[idx] = excl; }
        __syncthreads();
        if (threadIdx.x == 0) carry += tot;
        __syncthreads();
    }
    if (threadIdx.x == 0) ptr[n] = carry;
}

// placement with packed (src, val) int2 payload: one 8B scattered store per edge per direction
__global__ __launch_bounds__(256) void k_place(const int* __restrict__ row, const int* __restrict__ col,
                                               const float* __restrict__ adj, int nnz,
                                               int* nxt_col, int2* __restrict__ cs_pack,
                                               int* nxt_row, int2* __restrict__ rv_pack) {
    int i0 = blockIdx.x * blockDim.x + threadIdx.x;
    int stride = gridDim.x * blockDim.x;
    for (int i = i0; i < nnz; i += stride) {
        int r = row[i], c = col[i];
        int vb = __float_as_int(fabsf(adj[i]));
        int p = atomicAdd(&nxt_col[c], 1);
        cs_pack[p] = make_int2(r, vb);
        int q = atomicAdd(&nxt_row[r], 1);
        rv_pack[q] = make_int2(c, vb);
    }
}

// ---------------- feature init ----------------

__global__ __launch_bounds__(256) void k_ones(float4* p, int n4) {
    int i0 = blockIdx.x * blockDim.x + threadIdx.x;
    int stride = gridDim.x * blockDim.x;
    float4 one = make_float4(1.f, 1.f, 1.f, 1.f);
    for (int i = i0; i < n4; i += stride) p[i] = one;
}

// ---------------- prepare_cond: 1 -> 128 relu -> 64, 64-row tiles ----------------
__global__ __launch_bounds__(256) void k_pc2(const float* __restrict__ cond, float* __restrict__ constraints,
                                             int C,
                                             const float* __restrict__ w1, const float* __restrict__ b1,
                                             const float* __restrict__ w2, const float* __restrict__ b2) {
    __shared__ float hs[64][132];
    __shared__ float cs[64];
    const int t = threadIdx.x;
    const int base = blockIdx.x * 64;
    const int rem = C - base;

    if (t < 64) cs[t] = (t < rem) ? cond[base + t] : 0.f;
    __syncthreads();

    // layer 1: hs[row][k] = relu(cond[row]*w1[k] + b1[k])
    #pragma unroll
    for (int j = 0; j < 32; j++) {
        int idx = j * 256 + t;
        int k = idx & 127, row = idx >> 7;
        hs[row][k] = fmaxf(fmaf(cs[row], w1[k], b1[k]), 0.f);
    }
    __syncthreads();

    // layer 2: 64 cols; thread = (tx2 col-quad, ty2 row-quad)
    const int tx2 = t & 15, ty2 = t >> 4;
    float4 bb = ld4(b2 + tx2 * 4);
    float4 acc[4] = { bb, bb, bb, bb };
    const float* w2p = w2 + tx2 * 4;
    #pragma unroll 4
    for (int k = 0; k < 128; k++) {
        float4 w = ld4(w2p + k * 64);
        fma4(acc[0], hs[ty2 * 4 + 0][k], w);
        fma4(acc[1], hs[ty2 * 4 + 1][k], w);
        fma4(acc[2], hs[ty2 * 4 + 2][k], w);
        fma4(acc[3], hs[ty2 * 4 + 3][k], w);
    }
    #pragma unroll
    for (int r = 0; r < 4; r++) {
        int row = ty2 * 4 + r;
        if (row < rem) st4(&constraints[(size_t)(base + row) * 64 + tx2 * 4], acc[r]);
    }
}

// ---------------- segment-sum (gather form), packed payload ----------------
__global__ __launch_bounds__(256) void k_gather(const int* __restrict__ ptr,
                                                const int2* __restrict__ pack,
                                                const float* __restrict__ src_feat,
                                                float* __restrict__ dst_feat, int n) {
    int wid = (int)((blockIdx.x * blockDim.x + threadIdx.x) >> 6);
    int lane = threadIdx.x & 63;
    int nw = (int)((gridDim.x * blockDim.x) >> 6);
    for (int d = wid; d < n; d += nw) {
        int s = ptr[d], e = ptr[d + 1];
        float a0 = 0.f, a1 = 0.f;
        int i = s;
        for (; i + 1 < e; i += 2) {
            int2 e0 = pack[i], e1 = pack[i + 1];
            a0 = fmaf(__int_as_float(e0.y), src_feat[(size_t)e0.x * 64 + lane], a0);
            a1 = fmaf(__int_as_float(e1.y), src_feat[(size_t)e1.x * 64 + lane], a1);
        }
        if (i < e) {
            int2 e0 = pack[i];
            a0 = fmaf(__int_as_float(e0.y), src_feat[(size_t)e0.x * 64 + lane], a0);
        }
        dst_feat[(size_t)d * 64 + lane] = a0 + a1;
    }
}

// ---------------- update MLP: concat(feat,msg)[128] -> 128 relu -> 64, in-place, 64-row tiles
// 256 threads; X staged K-major xs[k][row]; weights streamed from L2.
__global__ __launch_bounds__(256) void k_mlp2(float* __restrict__ feat, const float* __restrict__ msg,
                                              int n,
                                              const float* __restrict__ w1, const float* __restrict__ b1,
                                              const float* __restrict__ w2, const float* __restrict__ b2) {
    __shared__ float xs[128][68];   // [k][row]
    __shared__ float hs[64][132];   // [row][hidden]
    const int t = threadIdx.x;
    const int base = blockIdx.x * 64;
    const int rem = n - base;

    // stage X
    {
        const float4* f4 = (const float4*)(feat + (size_t)base * 64);
        const float4* m4 = (const float4*)(msg + (size_t)base * 64);
        #pragma unroll
        for (int j = 0; j < 4; j++) {
            int idx = j * 256 + t;          // 0..1023
            int row = idx >> 4;             // 0..63
            int kq  = idx & 15;
            float4 v = (row < rem) ? f4[row * 16 + kq] : make_float4(0, 0, 0, 0);
            xs[kq * 4 + 0][row] = v.x; xs[kq * 4 + 1][row] = v.y;
            xs[kq * 4 + 2][row] = v.z; xs[kq * 4 + 3][row] = v.w;
            float4 u = (row < rem) ? m4[row * 16 + kq] : make_float4(0, 0, 0, 0);
            xs[64 + kq * 4 + 0][row] = u.x; xs[64 + kq * 4 + 1][row] = u.y;
            xs[64 + kq * 4 + 2][row] = u.z; xs[64 + kq * 4 + 3][row] = u.w;
        }
    }
    __syncthreads();

    // layer 1: H[64][128]; thread = (tx col-quad of 32, ty row-octet of 8)
    const int tx = t & 31, ty = t >> 5;
    {
        float4 bb = ld4(b1 + tx * 4);
        float4 acc[8];
        #pragma unroll
        for (int r = 0; r < 8; r++) acc[r] = bb;
        const float* w1p = w1 + tx * 4;
        #pragma unroll 4
        for (int k = 0; k < 128; k++) {
            float4 w  = ld4(w1p + k * 128);
            float4 xa = ld4(&xs[k][ty * 8]);
            float4 xb = ld4(&xs[k][ty * 8 + 4]);
            fma4(acc[0], xa.x, w); fma4(acc[1], xa.y, w);
            fma4(acc[2], xa.z, w); fma4(acc[3], xa.w, w);
            fma4(acc[4], xb.x, w); fma4(acc[5], xb.y, w);
            fma4(acc[6], xb.z, w); fma4(acc[7], xb.w, w);
        }
        #pragma unroll
        for (int r = 0; r < 8; r++) {
            float4 h;
            h.x = fmaxf(acc[r].x, 0.f); h.y = fmaxf(acc[r].y, 0.f);
            h.z = fmaxf(acc[r].z, 0.f); h.w = fmaxf(acc[r].w, 0.f);
            st4(&hs[ty * 8 + r][tx * 4], h);
        }
    }
    __syncthreads();

    // layer 2: Y[64][64]; thread = (tx2 col-quad of 16, ty2 row-quad of 16)
    const int tx2 = t & 15, ty2 = t >> 4;
    {
        float4 bb = ld4(b2 + tx2 * 4);
        float4 acc[4] = { bb, bb, bb, bb };
        const float* w2p = w2 + tx2 * 4;
        #pragma unroll 4
        for (int k = 0; k < 128; k++) {
            float4 w = ld4(w2p + k * 64);
            fma4(acc[0], hs[ty2 * 4 + 0][k], w);
            fma4(acc[1], hs[ty2 * 4 + 1][k], w);
            fma4(acc[2], hs[ty2 * 4 + 2][k], w);
            fma4(acc[3], hs[ty2 * 4 + 3][k], w);
        }
        #pragma unroll
        for (int r = 0; r < 4; r++) {
            int row = ty2 * 4 + r;
            if (row < rem) st4(&feat[(size_t)(base + row) * 64 + tx2 * 4], acc[r]);
        }
    }
}

// ---------------- output MLP: 64 -> 128 relu -> 16, sigmoid, 64-row tiles ----------------
__global__ __launch_bounds__(256) void k_out2(const float* __restrict__ vars, float* __restrict__ out, int V,
                                              const float* __restrict__ w1, const float* __restrict__ b1,
                                              const float* __restrict__ w2, const float* __restrict__ b2) {
    __shared__ float xs[64][68];    // [k][row]
    __shared__ float hs[64][132];   // [row][hidden]
    const int t = threadIdx.x;
    const int base = blockIdx.x * 64;
    const int rem = V - base;

    {
        const float4* v4 = (const float4*)(vars + (size_t)base * 64);
        #pragma unroll
        for (int j = 0; j < 4; j++) {
            int idx = j * 256 + t;
            int row = idx >> 4;
            int kq  = idx & 15;
            float4 v = (row < rem) ? v4[row * 16 + kq] : make_float4(0, 0, 0, 0);
            xs[kq * 4 + 0][row] = v.x; xs[kq * 4 + 1][row] = v.y;
            xs[kq * 4 + 2][row] = v.z; xs[kq * 4 + 3][row] = v.w;
        }
    }
    __syncthreads();

    // layer 1: K=64
    const int tx = t & 31, ty = t >> 5;
    {
        float4 bb = ld4(b1 + tx * 4);
        float4 acc[8];
        #pragma unroll
        for (int r = 0; r < 8; r++) acc[r] = bb;
        const float* w1p = w1 + tx * 4;
        #pragma unroll 4
        for (int k = 0; k < 64; k++) {
            float4 w  = ld4(w1p + k * 128);
            float4 xa = ld4(&xs[k][ty * 8]);
            float4 xb = ld4(&xs[k][ty * 8 + 4]);
            fma4(acc[0], xa.x, w); fma4(acc[1], xa.y, w);
            fma4(acc[2], xa.z, w); fma4(acc[3], xa.w, w);
            fma4(acc[4], xb.x, w); fma4(acc[5], xb.y, w);
            fma4(acc[6], xb.z, w); fma4(acc[7], xb.w, w);
        }
        #pragma unroll
        for (int r = 0; r < 8; r++) {
            float4 h;
            h.x = fmaxf(acc[r].x, 0.f); h.y = fmaxf(acc[r].y, 0.f);
            h.z = fmaxf(acc[r].z, 0.f); h.w = fmaxf(acc[r].w, 0.f);
            st4(&hs[ty * 8 + r][tx * 4], h);
        }
    }
    __syncthreads();

    // layer 2: 16 cols; thread = (tx3 col-quad of 4, ty3 row of 64)
    const int tx3 = t & 3, ty3 = t >> 2;
    {
        float4 o = ld4(b2 + tx3 * 4);
        const float* w2p = w2 + tx3 * 4;
        #pragma unroll 4
        for (int k = 0; k < 128; k++) {
            float4 w = ld4(w2p + k * 16);
            fma4(o, hs[ty3][k], w);
        }
        o.x = 1.f / (1.f + __expf(-o.x));
        o.y = 1.f / (1.f + __expf(-o.y));
        o.z = 1.f / (1.f + __expf(-o.z));
        o.w = 1.f / (1.f + __expf(-o.w));
        if (ty3 < rem) st4(&out[(size_t)(base + ty3) * 16 + tx3 * 4], o);
    }
}

// ---------------- launch ----------------

extern "C" void kernel_launch(void* const* d_in, const int* in_sizes, int n_in,
                              void* d_out, int out_size, void* d_ws, size_t ws_size,
                              hipStream_t stream) {
    const int*   row_idx = (const int*)d_in[0];
    const int*   col_idx = (const int*)d_in[1];
    const float* adj     = (const float*)d_in[2];
    const float* cond    = (const float*)d_in[3];
    const float* pc_w1  = (const float*)d_in[6];
    const float* pc_b1  = (const float*)d_in[7];
    const float* pc_w2  = (const float*)d_in[8];
    const float* pc_b2  = (const float*)d_in[9];
    const float* cu_w1  = (const float*)d_in[10];
    const float* cu_b1  = (const float*)d_in[11];
    const float* cu_w2  = (const float*)d_in[12];
    const float* cu_b2  = (const float*)d_in[13];
    const float* vu_w1  = (const float*)d_in[14];
    const float* vu_b1  = (const float*)d_in[15];
    const float* vu_w2  = (const float*)d_in[16];
    const float* vu_b2  = (const float*)d_in[17];
    const float* out_w1 = (const float*)d_in[18];
    const float* out_b1 = (const float*)d_in[19];
    const float* out_w2 = (const float*)d_in[20];
    const float* out_b2 = (const float*)d_in[21];

    const int NNZ = in_sizes[0];
    const int C   = in_sizes[3];
    const int V   = out_size / 16;

    float* out = (float*)d_out;

    // ---- workspace carve ----
    char* wsb = (char*)d_ws;
    size_t off = 0;
    auto carve = [&](size_t bytes) -> void* {
        void* p = wsb + off;
        off = (off + bytes + 255) & ~(size_t)255;
        return p;
    };
    float* variables   = (float*)carve((size_t)V * 64 * 4);
    float* constraints = (float*)carve((size_t)C * 64 * 4);
    float* v2c         = (float*)carve((size_t)C * 64 * 4);
    float* c2v         = (float*)carve((size_t)V * 64 * 4);
    int*   cnt_col     = (int*)carve((size_t)C * 4);
    int*   cnt_row     = (int*)carve((size_t)V * 4);
    int*   col_ptr     = (int*)carve((size_t)(C + 1) * 4);
    int*   row_ptr     = (int*)carve((size_t)(V + 1) * 4);
    int*   col_nxt     = (int*)carve((size_t)C * 4);
    int*   row_nxt     = (int*)carve((size_t)V * 4);
    int2*  cs_pack     = (int2*)carve((size_t)NNZ * 8);
    int2*  rv_pack     = (int2*)carve((size_t)NNZ * 8);
    (void)ws_size; (void)n_in;

    // ---- CSR build (both orientations) ----
    k_zero2<<<256, 256, 0, stream>>>(cnt_col, C, cnt_row, V);
    k_hist<<<2048, 256, 0, stream>>>(row_idx, col_idx, NNZ, cnt_row, cnt_col);
    k_scan2<<<2, 1024, 0, stream>>>(cnt_col, C, col_ptr, col_nxt,
                                    cnt_row, V, row_ptr, row_nxt);
    k_place<<<2048, 256, 0, stream>>>(row_idx, col_idx, adj, NNZ,
                                      col_nxt, cs_pack, row_nxt, rv_pack);

    // ---- init features ----
    k_ones<<<2048, 256, 0, stream>>>((float4*)variables, V * 16);
    k_pc2<<<(C + 63) / 64, 256, 0, stream>>>(cond, constraints, C, pc_w1, pc_b1, pc_w2, pc_b2);

    // ---- message-passing rounds ----
    for (int p = 0; p < 3; p++) {
        k_gather<<<2048, 256, 0, stream>>>(col_ptr, cs_pack, variables, v2c, C);
        k_mlp2<<<(C + 63) / 64, 256, 0, stream>>>(constraints, v2c, C, cu_w1, cu_b1, cu_w2, cu_b2);
        k_gather<<<2048, 256, 0, stream>>>(row_ptr, rv_pack, constraints, c2v, V);
        k_mlp2<<<(V + 63) / 64, 256, 0, stream>>>(variables, c2v, V, vu_w1, vu_b1, vu_w2, vu_b2);
    }

    // ---- output ----
    k_out2<<<(V + 63) / 64, 256, 0, stream>>>(variables, out, V, out_w1, out_b1, out_w2, out_b2);
}